// Round 2
// baseline (1178.106 us; speedup 1.0000x reference)
//
#include <hip/hip_runtime.h>
#include <hip/hip_bf16.h>

// MultiHeadAttention B=2 H=16 S=2048 D=128, fp32 I/O, bf16 MFMA internal.
// Round 2: fused two-sweep attention (rowsum sweep + normalize/write/PV sweep),
// bitfield mask, XOR-swizzled LDS, single write of the 537MB weights output.

using short8 = __attribute__((ext_vector_type(8))) short;
using f32x4  = __attribute__((ext_vector_type(4))) float;

#define DEVFN static __device__ __forceinline__

// XOR swizzle: permute 16B slots within a row by row&7 (breaks power-of-2 bank degeneracy)
#define SWZ256(row, colb) ((((row)) << 8) + ((colb) ^ ((((row)) & 7) << 4)))
#define SWZ128(row, colb) ((((row)) << 7) + ((colb) ^ ((((row)) & 7) << 4)))

DEVFN unsigned short f2bf(float f) {
    unsigned int u = __builtin_bit_cast(unsigned int, f);
    u += 0x7fffu + ((u >> 16) & 1u);   // RNE (no NaN inputs here)
    return (unsigned short)(u >> 16);
}
DEVFN float bf2f(unsigned short b) {
    unsigned int u = ((unsigned int)b) << 16;
    return __builtin_bit_cast(float, u);
}

// ---- stage ROWSx64 bf16 tile from global (row-major, ld elems) to LDS [ROWS][64] (linear)
template<int ROWS>
DEVFN void stage_bf16(const unsigned short* __restrict__ g, long ld,
                      unsigned short* lds, int tid) {
#pragma unroll
    for (int j = 0; j < ROWS / 32; ++j) {
        int c = tid + j * 256;
        int r = c >> 3, kc = (c & 7) << 3;
        *reinterpret_cast<uint4*>(lds + r * 64 + kc) =
            *reinterpret_cast<const uint4*>(g + (long)r * ld + kc);
    }
}

// ---- per-wave MFMA over one BK=64 K-tile (linear [row][64] LDS, used by k_qkv/k_out)
template<int MF, int NF>
DEVFN void mfma_tile(const unsigned short* As, const unsigned short* Bs,
                     f32x4 (&acc)[MF][NF], int lane) {
    int lr = lane & 15, lg = lane >> 4;
#pragma unroll
    for (int kk = 0; kk < 2; ++kk) {
        short8 a[MF], b[NF];
#pragma unroll
        for (int m = 0; m < MF; ++m)
            a[m] = *reinterpret_cast<const short8*>(As + (m * 16 + lr) * 64 + kk * 32 + lg * 8);
#pragma unroll
        for (int n = 0; n < NF; ++n)
            b[n] = *reinterpret_cast<const short8*>(Bs + (n * 16 + lr) * 64 + kk * 32 + lg * 8);
#pragma unroll
        for (int m = 0; m < MF; ++m)
#pragma unroll
            for (int n = 0; n < NF; ++n)
                acc[m][n] = __builtin_amdgcn_mfma_f32_16x16x32_bf16(a[m], b[n], acc[m][n], 0, 0, 0);
    }
}

// ---- k_prep: fp32->bf16 conversions (float4-vectorized) + zero the out region
__global__ __launch_bounds__(256) void k_prep(
        const float* __restrict__ x, const float* __restrict__ wq,
        const float* __restrict__ wk, const float* __restrict__ wv,
        const float* __restrict__ wd, float* __restrict__ out,
        unsigned short* __restrict__ xb, unsigned short* __restrict__ wqb,
        unsigned short* __restrict__ wkb, unsigned short* __restrict__ wvb,
        unsigned short* __restrict__ wdb) {
    int u = blockIdx.x * 256 + threadIdx.x;   // float4 units
    const float* src; unsigned short* dst; int off;
    if (u < 131072)       { src = x;  dst = xb;  off = u; }
    else if (u < 196608)  { src = wq; dst = wqb; off = u - 131072; }
    else if (u < 262144)  { src = wk; dst = wkb; off = u - 196608; }
    else if (u < 327680)  { src = wv; dst = wvb; off = u - 262144; }
    else if (u < 393216)  { src = wd; dst = wdb; off = u - 327680; }
    else {                // zero out region (atomicAdd target in k_out)
        float4 z = make_float4(0.f, 0.f, 0.f, 0.f);
        *reinterpret_cast<float4*>(out + (long)(u - 393216) * 4) = z;
        return;
    }
    float4 v = *reinterpret_cast<const float4*>(src + (long)off * 4);
    uint2 p;
    p.x = (unsigned int)f2bf(v.x) | ((unsigned int)f2bf(v.y) << 16);
    p.y = (unsigned int)f2bf(v.z) | ((unsigned int)f2bf(v.w) << 16);
    *reinterpret_cast<uint2*>(dst + (long)off * 4) = p;
}

// ---- k_mask: int32 mask -> bitfield (bit t of word = mask[...,t]!=0), 1MB total
__global__ __launch_bounds__(256) void k_mask(
        const int* __restrict__ mask, unsigned long long* __restrict__ bits) {
    int wave = (blockIdx.x * 256 + threadIdx.x) >> 6;
    int lane = threadIdx.x & 63;
#pragma unroll
    for (int i = 0; i < 16; ++i) {
        long w = (long)wave * 16 + i;
        unsigned long long bm = __ballot(mask[w * 64 + lane] != 0);
        if (lane == 0) bits[w] = bm;
    }
}

// ---- k_qkv: x(4096x128) @ W^T -> Q (scaled by 1/sqrt(D)), K rowmajor, V^T (B,H,D,S)
__global__ __launch_bounds__(256) void k_qkv(
        const unsigned short* __restrict__ xb, const unsigned short* __restrict__ wqb,
        const unsigned short* __restrict__ wkb, const unsigned short* __restrict__ wvb,
        const float* __restrict__ bq, const float* __restrict__ bk,
        const float* __restrict__ bv,
        unsigned short* __restrict__ Qb, unsigned short* __restrict__ Kb,
        unsigned short* __restrict__ Vtb) {
    __shared__ __align__(16) char smem[32768];
    unsigned short* As = (unsigned short*)smem;
    unsigned short* Bs = (unsigned short*)(smem + 16384);
    unsigned short* Cs = (unsigned short*)smem;   // reused after barrier
    int tid = threadIdx.x, lane = tid & 63, wid = tid >> 6;
    int wr = wid >> 1, wc = wid & 1;
    int lr = lane & 15, lg = lane >> 4;
    int mt = blockIdx.x, nt = blockIdx.y, z = blockIdx.z;
    const unsigned short* Wb = (z == 0) ? wqb : ((z == 1) ? wkb : wvb);
    const float* bias = (z == 0) ? bq : ((z == 1) ? bk : bv);
    const unsigned short* gA = xb + (long)mt * 128 * 128;
    const unsigned short* gB = Wb + (long)nt * 128 * 128;
    float scl = (z == 0) ? 0.08838834764831845f : 1.0f;  // fold 1/sqrt(D) into Q
    f32x4 acc[4][4] = {};
#pragma unroll
    for (int kt = 0; kt < 2; ++kt) {
        __syncthreads();
        stage_bf16<128>(gA + kt * 64, 128, As, tid);
        stage_bf16<128>(gB + kt * 64, 128, Bs, tid);
        __syncthreads();
        mfma_tile<4, 4>(As + wr * 64 * 64, Bs + wc * 64 * 64, acc, lane);
    }
    __syncthreads();
#pragma unroll
    for (int n = 0; n < 4; ++n) {
        int col = wc * 64 + n * 16 + lr;
        float bval = bias[nt * 128 + col];
#pragma unroll
        for (int m = 0; m < 4; ++m)
#pragma unroll
            for (int r = 0; r < 4; ++r) {
                int row = wr * 64 + m * 16 + lg * 4 + r;
                Cs[row * 128 + col] = f2bf((acc[m][n][r] + bval) * scl);
            }
    }
    __syncthreads();
    int rg0 = mt * 128;
    int b = rg0 >> 11, s0 = rg0 & 2047, h = nt;
    if (z < 2) {
        unsigned short* dst = ((z == 0) ? Qb : Kb) + ((long)(b * 16 + h) * 2048 + s0) * 128;
#pragma unroll
        for (int j = 0; j < 8; ++j) {
            int c = tid + j * 256;
            int r = c >> 4, cc2 = (c & 15) << 3;
            *reinterpret_cast<uint4*>(dst + (long)r * 128 + cc2) =
                *reinterpret_cast<uint4*>(Cs + r * 128 + cc2);
        }
    } else {
        unsigned short* dst = Vtb + (long)(b * 16 + h) * 128 * 2048;
#pragma unroll
        for (int j = 0; j < 8; ++j) {
            int c = tid + j * 256;
            int d = c >> 4, sl = (c & 15) << 3;
            unsigned int w0 = (unsigned int)Cs[(sl + 0) * 128 + d] | ((unsigned int)Cs[(sl + 1) * 128 + d] << 16);
            unsigned int w1 = (unsigned int)Cs[(sl + 2) * 128 + d] | ((unsigned int)Cs[(sl + 3) * 128 + d] << 16);
            unsigned int w2 = (unsigned int)Cs[(sl + 4) * 128 + d] | ((unsigned int)Cs[(sl + 5) * 128 + d] << 16);
            unsigned int w3 = (unsigned int)Cs[(sl + 6) * 128 + d] | ((unsigned int)Cs[(sl + 7) * 128 + d] << 16);
            *reinterpret_cast<uint4*>(dst + (long)d * 2048 + s0 + sl) = make_uint4(w0, w1, w2, w3);
        }
    }
}

// ---- k_attn: per (s-block of 128, z): sweep1 rowsums in regs; sweep2 recompute,
//      normalize, write fp32 weights once, PV accumulate -> concat bf16
__global__ __launch_bounds__(256, 2) void k_attn(
        const unsigned short* __restrict__ Qb, const unsigned short* __restrict__ Kb,
        const unsigned short* __restrict__ Vtb,
        const unsigned long long* __restrict__ maskbits,
        float* __restrict__ wout, unsigned short* __restrict__ ccb) {
    __shared__ __align__(16) char smem[49152];
    char* Ks = smem;              // [64 t][256B] swizzled
    char* Vs = smem + 16384;      // [128 d][128B] swizzled
    char* Ps = smem + 32768;      // [128 s][128B] swizzled
    float* rs2 = (float*)(smem + 32768);
    int tid = threadIdx.x, lane = tid & 63, wid = tid >> 6;
    int wr = wid >> 1, wc = wid & 1;
    int lr = lane & 15, lg = lane >> 4;
    int s0 = blockIdx.x * 128, z = blockIdx.y, b = z >> 4, h = z & 15;
    const unsigned short* Qg = Qb + (long)z * 262144 + (long)s0 * 128;
    const unsigned short* Kg = Kb + (long)z * 262144;
    const unsigned short* Vg = Vtb + (long)z * 262144;
    const unsigned long long* mb = maskbits + (long)b * 65536 + (long)s0 * 32;

    // --- stage Q (128 rows x 256B, swizzled, into Ks+Vs area), load frags to regs
#pragma unroll
    for (int j = 0; j < 8; ++j) {
        int u = tid + j * 256;
        int row = u >> 4, sl = u & 15;
        *reinterpret_cast<uint4*>(smem + SWZ256(row, sl * 16)) =
            *reinterpret_cast<const uint4*>(Qg + u * 8);
    }
    __syncthreads();
    short8 aq[4][4];
#pragma unroll
    for (int m = 0; m < 4; ++m)
#pragma unroll
        for (int kk = 0; kk < 4; ++kk)
            aq[m][kk] = *reinterpret_cast<const short8*>(
                smem + SWZ256(wr * 64 + m * 16 + lr, kk * 64 + lg * 16));
    __syncthreads();

    uint4 kreg[4], vreg[4];
    // prefetch K tile 0 (tile is contiguous 8192 elems)
#pragma unroll
    for (int j = 0; j < 4; ++j) {
        int u = tid + j * 256;
        kreg[j] = *reinterpret_cast<const uint4*>(Kg + u * 8);
    }

    // ================= sweep 1: rowsums =================
    float psum[4][4] = {};
    for (int t = 0; t < 32; ++t) {
#pragma unroll
        for (int j = 0; j < 4; ++j) {
            int u = tid + j * 256;
            *reinterpret_cast<uint4*>(Ks + SWZ256(u >> 4, (u & 15) * 16)) = kreg[j];
        }
        if (t < 31) {
#pragma unroll
            for (int j = 0; j < 4; ++j) {
                int u = tid + j * 256;
                kreg[j] = *reinterpret_cast<const uint4*>(Kg + (t + 1) * 8192 + u * 8);
            }
        }
        __syncthreads();
        f32x4 sc[4][2] = {};
#pragma unroll
        for (int kk = 0; kk < 4; ++kk) {
            short8 bk0 = *reinterpret_cast<const short8*>(Ks + SWZ256(wc * 32 + lr,      kk * 64 + lg * 16));
            short8 bk1 = *reinterpret_cast<const short8*>(Ks + SWZ256(wc * 32 + 16 + lr, kk * 64 + lg * 16));
#pragma unroll
            for (int m = 0; m < 4; ++m) {
                sc[m][0] = __builtin_amdgcn_mfma_f32_16x16x32_bf16(aq[m][kk], bk0, sc[m][0], 0, 0, 0);
                sc[m][1] = __builtin_amdgcn_mfma_f32_16x16x32_bf16(aq[m][kk], bk1, sc[m][1], 0, 0, 0);
            }
        }
#pragma unroll
        for (int m = 0; m < 4; ++m)
#pragma unroll
            for (int r = 0; r < 4; ++r) {
                unsigned long long w = mb[(wr * 64 + m * 16 + lg * 4 + r) * 32 + t];
#pragma unroll
                for (int n = 0; n < 2; ++n) {
                    int bit = wc * 32 + n * 16 + lr;
                    float e = ((w >> bit) & 1ull) ? 0.0f : __expf(sc[m][n][r]);
                    psum[m][r] += e;
                }
            }
        __syncthreads();
    }

    // prefetch K,V tile 0 for sweep 2 (overlap with reduction)
#pragma unroll
    for (int j = 0; j < 4; ++j) {
        int u = tid + j * 256;
        kreg[j] = *reinterpret_cast<const uint4*>(Kg + u * 8);
        vreg[j] = *reinterpret_cast<const uint4*>(Vg + (long)(u >> 3) * 2048 + (u & 7) * 8);
    }
    // reduce rowsums across lr lanes, then across wc waves via LDS
#pragma unroll
    for (int m = 0; m < 4; ++m)
#pragma unroll
        for (int r = 0; r < 4; ++r) {
            float v = psum[m][r];
            v += __shfl_xor(v, 1); v += __shfl_xor(v, 2);
            v += __shfl_xor(v, 4); v += __shfl_xor(v, 8);
            if (lr == 0) rs2[wc * 128 + wr * 64 + m * 16 + lg * 4 + r] = v;
        }
    __syncthreads();
    float inv[4][4];
#pragma unroll
    for (int m = 0; m < 4; ++m)
#pragma unroll
        for (int r = 0; r < 4; ++r) {
            int row = wr * 64 + m * 16 + lg * 4 + r;
            inv[m][r] = 1.0f / (rs2[row] + rs2[128 + row]);
        }

    // ================= sweep 2: normalize + weights write + PV =================
    f32x4 ctx[4][4] = {};
    for (int t = 0; t < 32; ++t) {
#pragma unroll
        for (int j = 0; j < 4; ++j) {
            int u = tid + j * 256;
            *reinterpret_cast<uint4*>(Ks + SWZ256(u >> 4, (u & 15) * 16)) = kreg[j];
            *reinterpret_cast<uint4*>(Vs + SWZ128(u >> 3, (u & 7) * 16)) = vreg[j];
        }
        if (t < 31) {
#pragma unroll
            for (int j = 0; j < 4; ++j) {
                int u = tid + j * 256;
                kreg[j] = *reinterpret_cast<const uint4*>(Kg + (t + 1) * 8192 + u * 8);
                vreg[j] = *reinterpret_cast<const uint4*>(Vg + (long)(u >> 3) * 2048 + (t + 1) * 64 + (u & 7) * 8);
            }
        }
        __syncthreads();    // b1
        f32x4 sc[4][2] = {};
#pragma unroll
        for (int kk = 0; kk < 4; ++kk) {
            short8 bk0 = *reinterpret_cast<const short8*>(Ks + SWZ256(wc * 32 + lr,      kk * 64 + lg * 16));
            short8 bk1 = *reinterpret_cast<const short8*>(Ks + SWZ256(wc * 32 + 16 + lr, kk * 64 + lg * 16));
#pragma unroll
            for (int m = 0; m < 4; ++m) {
                sc[m][0] = __builtin_amdgcn_mfma_f32_16x16x32_bf16(aq[m][kk], bk0, sc[m][0], 0, 0, 0);
                sc[m][1] = __builtin_amdgcn_mfma_f32_16x16x32_bf16(aq[m][kk], bk1, sc[m][1], 0, 0, 0);
            }
        }
#pragma unroll
        for (int m = 0; m < 4; ++m)
#pragma unroll
            for (int r = 0; r < 4; ++r) {
                int row = wr * 64 + m * 16 + lg * 4 + r;
                unsigned long long w = mb[row * 32 + t];
#pragma unroll
                for (int n = 0; n < 2; ++n) {
                    int bit = wc * 32 + n * 16 + lr;
                    float p = ((w >> bit) & 1ull) ? 0.0f : __expf(sc[m][n][r]);
                    p *= inv[m][r];
                    *reinterpret_cast<unsigned short*>(
                        Ps + SWZ128(row, (wc * 32 + n * 16 + lr) * 2)) = f2bf(p);
                }
            }
        __syncthreads();    // b2
        // PV accumulate
#pragma unroll
        for (int kk = 0; kk < 2; ++kk) {
            short8 ap[4], bv[4];
#pragma unroll
            for (int m = 0; m < 4; ++m)
                ap[m] = *reinterpret_cast<const short8*>(Ps + SWZ128(wr * 64 + m * 16 + lr, kk * 64 + lg * 16));
#pragma unroll
            for (int n = 0; n < 4; ++n)
                bv[n] = *reinterpret_cast<const short8*>(Vs + SWZ128(wc * 64 + n * 16 + lr, kk * 64 + lg * 16));
#pragma unroll
            for (int m = 0; m < 4; ++m)
#pragma unroll
                for (int n = 0; n < 4; ++n)
                    ctx[m][n] = __builtin_amdgcn_mfma_f32_16x16x32_bf16(ap[m], bv[n], ctx[m][n], 0, 0, 0);
        }
        // weights store (fp32, from Ps bf16 -- single write of final weights)
        {
            float* wg = wout + (long)z * 4194304 + (long)s0 * 2048 + t * 64;
#pragma unroll
            for (int j = 0; j < 4; ++j) {
                int u = tid + j * 256;
                int row = u >> 3, sl = u & 7;
                uint4 pv = *reinterpret_cast<const uint4*>(Ps + SWZ128(row, sl * 16));
                float4 lo, hi;
                lo.x = bf2f((unsigned short)(pv.x & 0xffff)); lo.y = bf2f((unsigned short)(pv.x >> 16));
                lo.z = bf2f((unsigned short)(pv.y & 0xffff)); lo.w = bf2f((unsigned short)(pv.y >> 16));
                hi.x = bf2f((unsigned short)(pv.z & 0xffff)); hi.y = bf2f((unsigned short)(pv.z >> 16));
                hi.z = bf2f((unsigned short)(pv.w & 0xffff)); hi.w = bf2f((unsigned short)(pv.w >> 16));
                float* dst = wg + (long)row * 2048 + sl * 8;
                *reinterpret_cast<float4*>(dst) = lo;
                *reinterpret_cast<float4*>(dst + 4) = hi;
            }
        }
        __syncthreads();    // b3 (protect Ks/Vs/Ps for next iter's staging)
    }

    // --- epilogue: ctx -> bf16 concat (B,S,H*D)
    unsigned short* Cs = (unsigned short*)smem;   // 128x128 linear
#pragma unroll
    for (int m = 0; m < 4; ++m)
#pragma unroll
        for (int n = 0; n < 4; ++n)
#pragma unroll
            for (int r = 0; r < 4; ++r)
                Cs[(wr * 64 + m * 16 + lg * 4 + r) * 128 + wc * 64 + n * 16 + lr] = f2bf(ctx[m][n][r]);
    __syncthreads();
    unsigned short* og = ccb + ((long)b * 2048 + s0) * 2048 + h * 128;
#pragma unroll
    for (int j = 0; j < 8; ++j) {
        int u = tid + j * 256;
        int row = u >> 4, sl = u & 15;
        *reinterpret_cast<uint4*>(og + (long)row * 2048 + sl * 8) =
            *reinterpret_cast<const uint4*>(Cs + row * 128 + sl * 8);
    }
}

// ---- k_out: concat @ Wd^T + bd -> out fp32, K-split 4 with atomicAdd (out zeroed in k_prep)
__global__ __launch_bounds__(256) void k_out(
        const unsigned short* __restrict__ ccb, const unsigned short* __restrict__ wdb,
        const float* __restrict__ bd, float* __restrict__ out) {
    __shared__ __align__(16) char smem[24576];
    unsigned short* As = (unsigned short*)smem;            // 64x64x2
    unsigned short* Bs = (unsigned short*)(smem + 8192);   // 128x64x2
    int tid = threadIdx.x, lane = tid & 63, wid = tid >> 6;
    int wr = wid >> 1, wc = wid & 1;
    int lr = lane & 15, lg = lane >> 4;
    int mt = blockIdx.x, ks = blockIdx.y;
    const unsigned short* gA = ccb + (long)mt * 64 * 2048 + ks * 512;
    const unsigned short* gB = wdb + ks * 512;
    f32x4 acc[2][4] = {};
    for (int kt = 0; kt < 8; ++kt) {
        __syncthreads();
        stage_bf16<64>(gA + kt * 64, 2048, As, tid);
        stage_bf16<128>(gB + kt * 64, 2048, Bs, tid);
        __syncthreads();
        mfma_tile<2, 4>(As + wr * 32 * 64, Bs + wc * 64 * 64, acc, lane);
    }
#pragma unroll
    for (int n = 0; n < 4; ++n) {
        int col = wc * 64 + n * 16 + lr;
        float bval = (ks == 0) ? bd[col] : 0.0f;
#pragma unroll
        for (int m = 0; m < 2; ++m)
#pragma unroll
            for (int r = 0; r < 4; ++r) {
                int row = wr * 32 + m * 16 + lg * 4 + r;
                atomicAdd(out + (long)(mt * 64 + row) * 128 + col, acc[m][n][r] + bval);
            }
    }
}

extern "C" void kernel_launch(void* const* d_in, const int* in_sizes, int n_in,
                              void* d_out, int out_size, void* d_ws, size_t ws_size,
                              hipStream_t stream) {
    const float* x  = (const float*)d_in[0];
    const int* mask = (const int*)d_in[1];
    const float* Wq = (const float*)d_in[2];
    const float* bq = (const float*)d_in[3];
    const float* Wk = (const float*)d_in[4];
    const float* bk = (const float*)d_in[5];
    const float* Wv = (const float*)d_in[6];
    const float* bv = (const float*)d_in[7];
    const float* Wd = (const float*)d_in[8];
    const float* bd = (const float*)d_in[9];

    float* out  = (float*)d_out;
    float* wout = out + 524288;   // weights (B,H,S,S) fp32

    char* ws = (char*)d_ws;
    unsigned short* xb   = (unsigned short*)(ws + 0);          // 1MB (reused as maskbits later)
    unsigned short* wqb  = (unsigned short*)(ws + 1048576);
    unsigned short* wkb  = (unsigned short*)(ws + 1572864);
    unsigned short* wvb  = (unsigned short*)(ws + 2097152);
    unsigned short* wdb  = (unsigned short*)(ws + 2621440);
    unsigned short* Qb   = (unsigned short*)(ws + 3145728);    // 16.8MB
    unsigned short* Kb   = (unsigned short*)(ws + 19922944);
    unsigned short* Vtb  = (unsigned short*)(ws + 36700160);
    unsigned short* ccb  = (unsigned short*)(ws + 53477376);
    unsigned long long* maskbits = (unsigned long long*)(ws + 0);  // overlaps xb (dead after k_qkv)

    k_prep<<<2048, 256, 0, stream>>>(x, Wq, Wk, Wv, Wd, out, xb, wqb, wkb, wvb, wdb);
    k_qkv<<<dim3(32, 16, 3), 256, 0, stream>>>(xb, wqb, wkb, wvb, bq, bk, bv, Qb, Kb, Vtb);
    k_mask<<<2048, 256, 0, stream>>>(mask, maskbits);
    k_attn<<<dim3(16, 32), 256, 0, stream>>>(Qb, Kb, Vtb, maskbits, wout, ccb);
    k_out<<<dim3(64, 4), 256, 0, stream>>>(ccb, wdb, bd, out);
}